// Round 2
// 553.979 us; speedup vs baseline: 1.0728x; 1.0728x over previous
//
#include <hip/hip_runtime.h>

// Problem constants (fixed by reference)
#define M_TOK 8192   // tokens
#define NF    4096   // out features
#define KF    4096   // in features
#define BK    64     // K-tile
#define NT    (KF / BK)   // 64 K-tiles

typedef __attribute__((ext_vector_type(8))) short bf16x8;  // 8 bf16 = 4 VGPRs
typedef __attribute__((ext_vector_type(4))) float f32x4;   // MFMA accumulator
typedef __attribute__((ext_vector_type(2))) short s16x2;   // packed bf16 pair

// ---------- helpers ----------
__device__ __forceinline__ unsigned short f2bf(float f) {
    unsigned u = __builtin_bit_cast(unsigned, f);
    u += 0x7FFFu + ((u >> 16) & 1u);   // round-to-nearest-even
    return (unsigned short)(u >> 16);
}

__device__ __forceinline__ float bf2f(unsigned short b) {
    unsigned u = ((unsigned)b) << 16;
    return __builtin_bit_cast(float, u);
}

__device__ __forceinline__ void load_lds16(const unsigned short* g, unsigned short* l) {
    // async global->LDS DMA: LDS dest = wave-uniform base + lane*16
    __builtin_amdgcn_global_load_lds(
        (const __attribute__((address_space(1))) unsigned int*)g,
        (__attribute__((address_space(3))) unsigned int*)l,
        16, 0, 0);
}

// raw workgroup barrier that is also a COMPILER memory fence (the builtin alone
// is not a fence; __syncthreads would drain vmcnt(0) and kill the pipeline)
__device__ __forceinline__ void block_bar() {
    asm volatile("" ::: "memory");
    __builtin_amdgcn_s_barrier();
    asm volatile("" ::: "memory");
}

#define VMCNT(n) asm volatile("s_waitcnt vmcnt(" #n ")" ::: "memory")

// ---------- preprocessing ----------
// Fused: zero bf16 dense-W scratch + convert X fp32->bf16. One HBM-bound pass.
__global__ void prep_zero_convx(const float4* __restrict__ X, ushort4* __restrict__ Xb,
                                uint4* __restrict__ Wb, int nx4, int nwb) {
    int i = blockIdx.x * blockDim.x + threadIdx.x;
    if (i < nwb) Wb[i] = (uint4){0u, 0u, 0u, 0u};
    if (i < nx4) {
        float4 v = X[i];
        ushort4 o;
        o.x = f2bf(v.x); o.y = f2bf(v.y); o.z = f2bf(v.z); o.w = f2bf(v.w);
        Xb[i] = o;
    }
}

// Scatter COO directly into bf16 dense W. Duplicates sum atomically.
__global__ void scatter_bf16(const int* __restrict__ idx, const float* __restrict__ w,
                             unsigned short* __restrict__ Wb, int nnz) {
    int t = blockIdx.x * blockDim.x + threadIdx.x;
    if (t >= nnz) return;
    int r = idx[t];
    int c = idx[nnz + t];
    size_t elem = (size_t)r * KF + c;
#if __has_builtin(__builtin_amdgcn_global_atomic_fadd_v2bf16)
    unsigned short wb = f2bf(w[t]);
    s16x2 val;
    if (elem & 1) { val[0] = 0; val[1] = (short)wb; }
    else          { val[0] = (short)wb; val[1] = 0; }
    __builtin_amdgcn_global_atomic_fadd_v2bf16(
        (__attribute__((address_space(1))) s16x2*)(Wb + (elem & ~(size_t)1)), val);
#else
    unsigned* addr = (unsigned*)(Wb + (elem & ~(size_t)1));
    float wf = w[t];
    unsigned old = __hip_atomic_load(addr, __ATOMIC_RELAXED, __HIP_MEMORY_SCOPE_AGENT), assumed;
    do {
        assumed = old;
        unsigned short cur = (elem & 1) ? (unsigned short)(assumed >> 16)
                                        : (unsigned short)(assumed & 0xffffu);
        unsigned short nw = f2bf(bf2f(cur) + wf);
        unsigned newv = (elem & 1) ? ((assumed & 0x0000ffffu) | ((unsigned)nw << 16))
                                   : ((assumed & 0xffff0000u) | (unsigned)nw);
        old = atomicCAS(addr, assumed, newv);
    } while (old != assumed);
#endif
}

// ---------- GEMM: C[M,N] = A[M,K](bf16) * B[N,K]^T(bf16) + bias, fp32 out ----------
// 256x256 tile, BK=64, 512 threads = 8 waves (2M x 4N), each wave 128x64 output.
// 4 phases per K-tile, counted vmcnt (never 0 in main loop), raw s_barrier,
// setprio around MFMA clusters.
//
// LDS (128 KiB STATIC): buffer p at byte p*65536:
//   A region @0     : [h][256 rows][32 k] bf16 -> h*16384 + row*64B + pos*16B
//   B region @32768 : same
// Swizzle: 16B chunk c of row r stored at pos = c ^ ((r>>1)&3)  (2-way alias = free).
// Staging is LDS-linear (tid*16B); the swizzle is applied to the GLOBAL source chunk.
__global__ __launch_bounds__(512, 2) void gemm_bt_bias(
    const unsigned short* __restrict__ A,   // [M_TOK][KF] bf16
    const unsigned short* __restrict__ B,   // [NF][KF] bf16
    const float* __restrict__ bias,
    float* __restrict__ C)
{
    __shared__ unsigned short lds_u[65536];   // 131072 bytes (gfx950: 160 KiB LDS/CU)
    char* const ldsb = (char*)lds_u;

    const int tid  = threadIdx.x;
    const int lane = tid & 63;
    const int wave = tid >> 6;
    const int wm   = wave >> 2;   // 0..1
    const int wn   = wave & 3;    // 0..3

    // bijective XCD swizzle: nwg=512, bn-major flat id; 64 consecutive tiles per XCD
    // = 2 B-panels (2x2MB) resident per XCD L2.
    const int flat = blockIdx.y * 32 + blockIdx.x;
    const int swz  = (flat & 7) * 64 + (flat >> 3);
    const int bm   = swz & 31;    // 0..31 (M tiles)
    const int bn   = swz >> 5;    // 0..15 (N tiles)

    f32x4 acc[8][4] = {};

    // ---- staging source addressing ----
    // per k-half slab instr: 512 threads x 16B = 128 rows x 64B; row = wave*16 + lane>>2
    const int gc   = (lane & 3) ^ ((lane >> 3) & 3);   // inverse-swizzled source chunk
    const int srow = wave * 16 + (lane >> 2);
    const unsigned short* gA   = A + (size_t)(bm * 256 + srow) * KF + gc * 8;
    const unsigned short* gB   = B + (size_t)(bn * 256 + srow) * KF + gc * 8;
    const unsigned short* gAHi = gA + (size_t)128 * KF;
    const unsigned short* gBHi = gB + (size_t)128 * KF;

    unsigned short* const sdus = lds_u + wave * 512;   // wave-uniform dest (+1024B/wave)

    // ---- LDS fragment-read addressing (constant through K loop) ----
    // A-frag 16x16x32: lane holds [m = lane&15][k = (lane>>4)*8 + j]
    const int fr    = lane & 15;
    const int quad  = lane >> 4;
    const int pos16 = (quad ^ ((fr >> 1) & 3)) << 4;          // swizzled 16B pos (bytes)
    const int rdA   = (wm * 128 + fr) * 64 + pos16;           // + h*16384 + i*1024 (+pb*65536)
    const int rdB   = 32768 + (wn * 64 + fr) * 64 + pos16;    // + h*16384 + j*1024

#define STAGE(gp, gpHi, region, pbuf, h) do { \
    load_lds16((gp)   + (h) * 32, sdus + (((pbuf) * 65536 + (region) + (h) * 16384       ) >> 1)); \
    load_lds16((gpHi) + (h) * 32, sdus + (((pbuf) * 65536 + (region) + (h) * 16384 + 8192) >> 1)); \
} while (0)

#define RD_A4(dst, pbuf, h, i0) do { \
    _Pragma("unroll") \
    for (int _i = 0; _i < 4; ++_i) \
        dst[_i] = *(const bf16x8*)(ldsb + (pbuf) * 65536 + (h) * 16384 + rdA + ((i0) + _i) * 1024); \
} while (0)

#define RD_B4(dst, pbuf, h) do { \
    _Pragma("unroll") \
    for (int _j = 0; _j < 4; ++_j) \
        dst[_j] = *(const bf16x8*)(ldsb + (pbuf) * 65536 + (h) * 16384 + rdB + _j * 1024); \
} while (0)

#define MFMA16(i0, af, bfv) do { \
    _Pragma("unroll") \
    for (int _i = 0; _i < 4; ++_i) \
        _Pragma("unroll") \
        for (int _j = 0; _j < 4; ++_j) \
            acc[(i0) + _i][_j] = __builtin_amdgcn_mfma_f32_16x16x32_bf16(af[_i], bfv[_j], acc[(i0) + _i][_j], 0, 0, 0); \
} while (0)

    // ---- prologue: stage tile 0 (Ah0,Bh0,Ah1,Bh1 = 8 loads) into buf 0 ----
    STAGE(gA, gAHi, 0,     0, 0);
    STAGE(gB, gBHi, 32768, 0, 0);
    STAGE(gA, gAHi, 0,     0, 1);
    STAGE(gB, gBHi, 32768, 0, 1);
    gA += BK; gB += BK; gAHi += BK; gBHi += BK;
    VMCNT(4);            // Ah0,Bh0(0) landed; Ah1,Bh1(0) still in flight
    block_bar();

    // ---- main loop: tiles 0..62, staging tile t+1; vmcnt(4) twice per tile ----
    int pb = 0;
#pragma unroll 1
    for (int t = 0; t < NT - 1; ++t) {
        const int nb = pb ^ 1;
        bf16x8 a[4], b[4];
        // phase 1: frags A[0..3]h0 + B[0..3]h0 ; prefetch Ah0(t+1)
        RD_A4(a, pb, 0, 0);
        RD_B4(b, pb, 0);
        STAGE(gA, gAHi, 0, nb, 0);
        block_bar();
        __builtin_amdgcn_s_setprio(1);
        MFMA16(0, a, b);
        __builtin_amdgcn_s_setprio(0);
        block_bar();
        // phase 2: frags A[4..7]h0 (B reused) ; prefetch Bh0(t+1)
        RD_A4(a, pb, 0, 4);
        STAGE(gB, gBHi, 32768, nb, 0);
        block_bar();
        __builtin_amdgcn_s_setprio(1);
        MFMA16(4, a, b);
        __builtin_amdgcn_s_setprio(0);
        VMCNT(4);        // Ah1,Bh1(t) landed; Ah0,Bh0(t+1) in flight
        block_bar();
        // phase 3: frags A[0..3]h1 + B[0..3]h1 ; prefetch Ah1(t+1)
        RD_A4(a, pb, 1, 0);
        RD_B4(b, pb, 1);
        STAGE(gA, gAHi, 0, nb, 1);
        block_bar();
        __builtin_amdgcn_s_setprio(1);
        MFMA16(0, a, b);
        __builtin_amdgcn_s_setprio(0);
        block_bar();
        // phase 4: frags A[4..7]h1 ; prefetch Bh1(t+1)
        RD_A4(a, pb, 1, 4);
        STAGE(gB, gBHi, 32768, nb, 1);
        block_bar();
        __builtin_amdgcn_s_setprio(1);
        MFMA16(4, a, b);
        __builtin_amdgcn_s_setprio(0);
        VMCNT(4);        // Ah0,Bh0(t+1) landed; Ah1,Bh1(t+1) in flight
        block_bar();
        gA += BK; gB += BK; gAHi += BK; gBHi += BK;
        pb = nb;
    }

    // ---- last K-tile: no staging; single counted drain mid-tile ----
    {
        bf16x8 a[4], b[4];
        RD_A4(a, pb, 0, 0);
        RD_B4(b, pb, 0);
        MFMA16(0, a, b);
        RD_A4(a, pb, 0, 4);
        MFMA16(4, a, b);
        VMCNT(0);        // Ah1,Bh1(63): the only 4 outstanding
        block_bar();
        RD_A4(a, pb, 1, 0);
        RD_B4(b, pb, 1);
        MFMA16(0, a, b);
        RD_A4(a, pb, 1, 4);
        MFMA16(4, a, b);
    }

#undef STAGE
#undef RD_A4
#undef RD_B4
#undef MFMA16

    // ---- epilogue: C/D layout col = lane&15, row = (lane>>4)*4 + reg ----
    const int crow = bm * 256 + wm * 128;
    const int ccol = bn * 256 + wn * 64;
    const int r_l  = quad * 4;
#pragma unroll
    for (int j = 0; j < 4; ++j) {
        int col = ccol + j * 16 + fr;
        float bv = bias[col];
#pragma unroll
        for (int i = 0; i < 8; ++i) {
#pragma unroll
            for (int r = 0; r < 4; ++r)
                C[(size_t)(crow + i * 16 + r_l + r) * NF + col] = acc[i][j][r] + bv;
        }
    }
}

// ---------- launch ----------
extern "C" void kernel_launch(void* const* d_in, const int* in_sizes, int n_in,
                              void* d_out, int out_size, void* d_ws, size_t ws_size,
                              hipStream_t stream) {
    const float* x    = (const float*)d_in[0];
    const float* w    = (const float*)d_in[1];
    const float* bias = (const float*)d_in[2];
    const int*   idx  = (const int*)d_in[3];
    float* out = (float*)d_out;
    const int nnz = in_sizes[1];

    // Scratch layout in ws:
    //  - ws + 0      : W bf16  (32MB)
    //  - ws + 32MB   : X bf16  (64MB)
    unsigned short* Wb = (unsigned short*)d_ws;
    unsigned short* Xb = (unsigned short*)((char*)d_ws + (size_t)NF * KF * sizeof(unsigned short));

    const int nx4 = M_TOK * KF / 4;           // X in float4 units
    const int nwb = NF * KF * 2 / 16;         // W bf16 in uint4 units

    // 1) fused: zero bf16 W + convert X -> bf16
    prep_zero_convx<<<(nx4 + 255) / 256, 256, 0, stream>>>(
        (const float4*)x, (ushort4*)Xb, (uint4*)Wb, nx4, nwb);
    // 2) scatter COO straight into bf16 W (duplicates sum via packed-bf16 atomics)
    scatter_bf16<<<(nnz + 255) / 256, 256, 0, stream>>>(idx, w, Wb, nnz);
    // 3) GEMM + bias (overwrites all of d_out; static 128 KiB LDS, no attribute call)
    gemm_bt_bias<<<dim3(32, 16), 512, 0, stream>>>(Xb, Wb, bias, out);
}

// Round 3
// 537.421 us; speedup vs baseline: 1.1058x; 1.0308x over previous
//
#include <hip/hip_runtime.h>

// Problem constants (fixed by reference)
#define M_TOK 8192   // tokens
#define NF    4096   // out features
#define KF    4096   // in features
#define BK    64     // K-tile
#define NHALF 128    // 128 half-tiles of 32 k each

typedef __attribute__((ext_vector_type(8))) short bf16x8;  // 8 bf16 = 4 VGPRs
typedef __attribute__((ext_vector_type(4))) float f32x4;   // MFMA accumulator
typedef __attribute__((ext_vector_type(2))) short s16x2;   // packed bf16 pair

// ---------- helpers ----------
__device__ __forceinline__ unsigned short f2bf(float f) {
    unsigned u = __builtin_bit_cast(unsigned, f);
    u += 0x7FFFu + ((u >> 16) & 1u);   // round-to-nearest-even
    return (unsigned short)(u >> 16);
}

__device__ __forceinline__ float bf2f(unsigned short b) {
    unsigned u = ((unsigned)b) << 16;
    return __builtin_bit_cast(float, u);
}

__device__ __forceinline__ void load_lds16(const unsigned short* g, unsigned short* l) {
    // async global->LDS DMA: LDS dest = wave-uniform base + lane*16
    __builtin_amdgcn_global_load_lds(
        (const __attribute__((address_space(1))) unsigned int*)g,
        (__attribute__((address_space(3))) unsigned int*)l,
        16, 0, 0);
}

// raw workgroup barrier that is also a COMPILER memory fence
__device__ __forceinline__ void block_bar() {
    asm volatile("" ::: "memory");
    __builtin_amdgcn_s_barrier();
    asm volatile("" ::: "memory");
}

#define VMCNT(n) asm volatile("s_waitcnt vmcnt(" #n ")" ::: "memory")

// ---------- preprocessing ----------
// Fused: zero bf16 dense-W scratch + convert X fp32->bf16. One HBM-bound pass.
__global__ void prep_zero_convx(const float4* __restrict__ X, ushort4* __restrict__ Xb,
                                uint4* __restrict__ Wb, int nx4, int nwb) {
    int i = blockIdx.x * blockDim.x + threadIdx.x;
    if (i < nwb) Wb[i] = (uint4){0u, 0u, 0u, 0u};
    if (i < nx4) {
        float4 v = X[i];
        ushort4 o;
        o.x = f2bf(v.x); o.y = f2bf(v.y); o.z = f2bf(v.z); o.w = f2bf(v.w);
        Xb[i] = o;
    }
}

// Scatter COO directly into bf16 dense W. Duplicates sum atomically.
__global__ void scatter_bf16(const int* __restrict__ idx, const float* __restrict__ w,
                             unsigned short* __restrict__ Wb, int nnz) {
    int t = blockIdx.x * blockDim.x + threadIdx.x;
    if (t >= nnz) return;
    int r = idx[t];
    int c = idx[nnz + t];
    size_t elem = (size_t)r * KF + c;
#if __has_builtin(__builtin_amdgcn_global_atomic_fadd_v2bf16)
    unsigned short wb = f2bf(w[t]);
    s16x2 val;
    if (elem & 1) { val[0] = 0; val[1] = (short)wb; }
    else          { val[0] = (short)wb; val[1] = 0; }
    __builtin_amdgcn_global_atomic_fadd_v2bf16(
        (__attribute__((address_space(1))) s16x2*)(Wb + (elem & ~(size_t)1)), val);
#else
    unsigned* addr = (unsigned*)(Wb + (elem & ~(size_t)1));
    float wf = w[t];
    unsigned old = __hip_atomic_load(addr, __ATOMIC_RELAXED, __HIP_MEMORY_SCOPE_AGENT), assumed;
    do {
        assumed = old;
        unsigned short cur = (elem & 1) ? (unsigned short)(assumed >> 16)
                                        : (unsigned short)(assumed & 0xffffu);
        unsigned short nw = f2bf(bf2f(cur) + wf);
        unsigned newv = (elem & 1) ? ((assumed & 0x0000ffffu) | ((unsigned)nw << 16))
                                   : ((assumed & 0xffff0000u) | (unsigned)nw);
        old = atomicCAS(addr, assumed, newv);
    } while (old != assumed);
#endif
}

// ---------- GEMM: C[M,N] = A[M,K](bf16) * B[N,K]^T(bf16) + bias, fp32 out ----------
// 256x256 tile, 512 threads = 8 waves (2M x 4N), each wave 128x64 output.
// Half-tile (32-k) pipeline: 4 LDS slots x 32 KB, 3 halves prefetched ahead,
// one counted vmcnt(8) per half (never 0 in main loop), raw s_barrier,
// setprio around MFMA clusters. 2 phases of 16 MFMA per half.
//
// LDS slot s at byte s*32768: A-half @0 (256 rows x 32k: row*64B), B-half @16384.
// Swizzle: 16B chunk c of row r stored at pos = c ^ ((r>>1)&3) (2-way alias = free).
// Staging is LDS-linear (tid*16B); swizzle applied to the GLOBAL source chunk.
__global__ __launch_bounds__(512, 2) void gemm_bt_bias(
    const unsigned short* __restrict__ A,   // [M_TOK][KF] bf16
    const unsigned short* __restrict__ B,   // [NF][KF] bf16
    const float* __restrict__ bias,
    float* __restrict__ C)
{
    __shared__ unsigned short lds_u[65536];   // 131072 B = 4 slots x 32 KB
    char* const ldsb = (char*)lds_u;

    const int tid  = threadIdx.x;
    const int lane = tid & 63;
    const int wave = tid >> 6;
    const int wm   = wave >> 2;   // 0..1
    const int wn   = wave & 3;    // 0..3

    // 2D XCD partition (bijective): XCD x owns bm in [(x&3)*8,+8), bn in [(x>>2)*8,+8).
    // 32 concurrent blocks/XCD cover 8 A-panels x 4 B-panels -> per-K-step slab
    // working set 384 KB, L2-resident. A fetched 2x, B 4x total.
    const int flat = blockIdx.y * 32 + blockIdx.x;
    const int xcd  = flat & 7;
    const int q    = flat >> 3;    // 0..63 within XCD
    const int bm   = (xcd & 3) * 8 + (q & 7);    // 0..31
    const int bn   = (xcd >> 2) * 8 + (q >> 3);  // 0..15

    f32x4 acc[8][4] = {};

    // ---- staging source addressing ----
    // per 8KB region instr: 512 threads x 16B = 128 rows x 64B; row = wave*16 + lane>>2
    const int gc   = (lane & 3) ^ ((lane >> 3) & 3);   // inverse-swizzled source chunk
    const int srow = wave * 16 + (lane >> 2);
    const unsigned short* gA   = A + (size_t)(bm * 256 + srow) * KF + gc * 8;
    const unsigned short* gB   = B + (size_t)(bn * 256 + srow) * KF + gc * 8;
    const unsigned short* gAHi = gA + (size_t)128 * KF;
    const unsigned short* gBHi = gB + (size_t)128 * KF;

    unsigned short* const sd = lds_u + wave * 512;   // wave-uniform dest (+1024B/wave)

    // ---- LDS fragment-read addressing ----
    // A-frag 16x16x32: lane holds [m = lane&15][k = (lane>>4)*8 + j]
    const int fr    = lane & 15;
    const int quad  = lane >> 4;
    const int pos16 = (quad ^ ((fr >> 1) & 3)) << 4;       // swizzled 16B pos (bytes)
    const int rdA   = (wm * 128 + fr) * 64 + pos16;        // + slot_byte + i*1024
    const int rdB   = 16384 + (wn * 64 + fr) * 64 + pos16; // + slot_byte + j*1024

// stage A-half / B-half of source k-offset ko (elements) into slot byte sb (2 loads each)
#define STAGE_A(sb, ko) do { \
    load_lds16(gA   + (ko), sd + (((sb)        ) >> 1)); \
    load_lds16(gAHi + (ko), sd + (((sb) +  8192) >> 1)); \
} while (0)
#define STAGE_B(sb, ko) do { \
    load_lds16(gB   + (ko), sd + (((sb) + 16384) >> 1)); \
    load_lds16(gBHi + (ko), sd + (((sb) + 24576) >> 1)); \
} while (0)

#define RD_A4(dst, sb, i0) do { \
    _Pragma("unroll") \
    for (int _i = 0; _i < 4; ++_i) \
        dst[_i] = *(const bf16x8*)(ldsb + (sb) + rdA + ((i0) + _i) * 1024); \
} while (0)

#define RD_B4(dst, sb) do { \
    _Pragma("unroll") \
    for (int _j = 0; _j < 4; ++_j) \
        dst[_j] = *(const bf16x8*)(ldsb + (sb) + rdB + _j * 1024); \
} while (0)

#define MFMA16(i0, af, bfv) do { \
    _Pragma("unroll") \
    for (int _i = 0; _i < 4; ++_i) \
        _Pragma("unroll") \
        for (int _j = 0; _j < 4; ++_j) \
            acc[(i0) + _i][_j] = __builtin_amdgcn_mfma_f32_16x16x32_bf16(af[_i], bfv[_j], acc[(i0) + _i][_j], 0, 0, 0); \
} while (0)

    // ---- prologue: stage halves 0,1,2 into slots 0,1,2 (12 loads) ----
    STAGE_A(0, 0);       STAGE_B(0, 0);
    STAGE_A(32768, 32);  STAGE_B(32768, 32);
    STAGE_A(65536, 64);  STAGE_B(65536, 64);
    VMCNT(8);            // half 0 landed; 1,2 in flight
    block_bar();

    // ---- main loop: halves g=0..124, staging half g+3; vmcnt(8) once per half ----
    int ko3 = 96;        // k-offset (elements) of half g+3
#pragma unroll 1
    for (int g = 0; g < NHALF - 3; ++g) {
        const int sb  = (g & 3) << 15;         // read slot
        const int sbn = ((g + 3) & 3) << 15;   // stage slot (freed at iter g-1)
        bf16x8 a[4], b[4];
        // phase 1: frags A[0..3] + B[0..3] ; stage A-half(g+3)
        RD_A4(a, sb, 0);
        RD_B4(b, sb);
        STAGE_A(sbn, ko3);
        block_bar();
        __builtin_amdgcn_s_setprio(1);
        MFMA16(0, a, b);
        __builtin_amdgcn_s_setprio(0);
        block_bar();
        // phase 2: frags A[4..7] (B reused) ; stage B-half(g+3)
        RD_A4(a, sb, 4);
        STAGE_B(sbn, ko3);
        block_bar();
        __builtin_amdgcn_s_setprio(1);
        MFMA16(4, a, b);
        __builtin_amdgcn_s_setprio(0);
        VMCNT(8);        // half g+1 landed; g+2, g+3 in flight
        block_bar();
        ko3 += 32;
    }

    // ---- epilogue halves 125,126,127: no staging; drain 8 -> 4 -> 0 ----
    {
        bf16x8 a[4], b[4];
        // g = 125 (slot 1)
        RD_A4(a, 32768, 0);
        RD_B4(b, 32768);
        block_bar();
        MFMA16(0, a, b);
        block_bar();
        RD_A4(a, 32768, 4);
        block_bar();
        MFMA16(4, a, b);
        VMCNT(4);        // half 126 landed
        block_bar();
        // g = 126 (slot 2)
        RD_A4(a, 65536, 0);
        RD_B4(b, 65536);
        block_bar();
        MFMA16(0, a, b);
        block_bar();
        RD_A4(a, 65536, 4);
        block_bar();
        MFMA16(4, a, b);
        VMCNT(0);        // half 127 landed
        block_bar();
        // g = 127 (slot 3)
        RD_A4(a, 98304, 0);
        RD_B4(b, 98304);
        MFMA16(0, a, b);
        RD_A4(a, 98304, 4);
        MFMA16(4, a, b);
    }

#undef STAGE_A
#undef STAGE_B
#undef RD_A4
#undef RD_B4
#undef MFMA16

    // ---- epilogue: C/D layout col = lane&15, row = (lane>>4)*4 + reg ----
    const int crow = bm * 256 + wm * 128;
    const int ccol = bn * 256 + wn * 64;
    const int r_l  = quad * 4;
#pragma unroll
    for (int j = 0; j < 4; ++j) {
        int col = ccol + j * 16 + fr;
        float bv = bias[col];
#pragma unroll
        for (int i = 0; i < 8; ++i) {
#pragma unroll
            for (int r = 0; r < 4; ++r)
                C[(size_t)(crow + i * 16 + r_l + r) * NF + col] = acc[i][j][r] + bv;
        }
    }
}

// ---------- launch ----------
extern "C" void kernel_launch(void* const* d_in, const int* in_sizes, int n_in,
                              void* d_out, int out_size, void* d_ws, size_t ws_size,
                              hipStream_t stream) {
    const float* x    = (const float*)d_in[0];
    const float* w    = (const float*)d_in[1];
    const float* bias = (const float*)d_in[2];
    const int*   idx  = (const int*)d_in[3];
    float* out = (float*)d_out;
    const int nnz = in_sizes[1];

    // Scratch layout in ws:
    //  - ws + 0      : W bf16  (32MB)
    //  - ws + 32MB   : X bf16  (64MB)
    unsigned short* Wb = (unsigned short*)d_ws;
    unsigned short* Xb = (unsigned short*)((char*)d_ws + (size_t)NF * KF * sizeof(unsigned short));

    const int nx4 = M_TOK * KF / 4;           // X in float4 units
    const int nwb = NF * KF * 2 / 16;         // W bf16 in uint4 units

    // 1) fused: zero bf16 W + convert X -> bf16
    prep_zero_convx<<<(nx4 + 255) / 256, 256, 0, stream>>>(
        (const float4*)x, (ushort4*)Xb, (uint4*)Wb, nx4, nwb);
    // 2) scatter COO straight into bf16 W (duplicates sum via packed-bf16 atomics)
    scatter_bf16<<<(nnz + 255) / 256, 256, 0, stream>>>(idx, w, Wb, nnz);
    // 3) GEMM + bias (overwrites all of d_out; static 128 KiB LDS)
    gemm_bt_bias<<<dim3(32, 16), 512, 0, stream>>>(Xb, Wb, bias, out);
}

// Round 4
// 527.786 us; speedup vs baseline: 1.1260x; 1.0183x over previous
//
#include <hip/hip_runtime.h>

// Problem constants (fixed by reference)
#define M_TOK 8192   // tokens
#define NF    4096   // out features
#define KF    4096   // in features
#define NHALF 128    // 128 half-tiles of 32 k each

typedef __attribute__((ext_vector_type(8))) short bf16x8;  // 8 bf16 = 4 VGPRs
typedef __attribute__((ext_vector_type(4))) float f32x4;   // MFMA accumulator
typedef __attribute__((ext_vector_type(2))) short s16x2;   // packed bf16 pair

// ---------- helpers ----------
__device__ __forceinline__ unsigned short f2bf(float f) {
    unsigned u = __builtin_bit_cast(unsigned, f);
    u += 0x7FFFu + ((u >> 16) & 1u);   // round-to-nearest-even
    return (unsigned short)(u >> 16);
}

__device__ __forceinline__ float bf2f(unsigned short b) {
    unsigned u = ((unsigned)b) << 16;
    return __builtin_bit_cast(float, u);
}

__device__ __forceinline__ void load_lds16(const unsigned short* g, unsigned short* l) {
    // async global->LDS DMA: LDS dest = wave-uniform base + lane*16
    __builtin_amdgcn_global_load_lds(
        (const __attribute__((address_space(1))) unsigned int*)g,
        (__attribute__((address_space(3))) unsigned int*)l,
        16, 0, 0);
}

// raw workgroup barrier that is also a COMPILER memory fence
__device__ __forceinline__ void block_bar() {
    asm volatile("" ::: "memory");
    __builtin_amdgcn_s_barrier();
    asm volatile("" ::: "memory");
}

#define VMCNT(n) asm volatile("s_waitcnt vmcnt(" #n ")" ::: "memory")

// ---------- preprocessing ----------
// Fused: zero bf16 dense-W scratch + convert X fp32->bf16. One HBM-bound pass.
__global__ void prep_zero_convx(const float4* __restrict__ X, ushort4* __restrict__ Xb,
                                uint4* __restrict__ Wb, int nx4, int nwb) {
    int i = blockIdx.x * blockDim.x + threadIdx.x;
    if (i < nwb) Wb[i] = (uint4){0u, 0u, 0u, 0u};
    if (i < nx4) {
        float4 v = X[i];
        ushort4 o;
        o.x = f2bf(v.x); o.y = f2bf(v.y); o.z = f2bf(v.z); o.w = f2bf(v.w);
        Xb[i] = o;
    }
}

// Scatter COO directly into bf16 dense W. Duplicates sum atomically.
__global__ void scatter_bf16(const int* __restrict__ idx, const float* __restrict__ w,
                             unsigned short* __restrict__ Wb, int nnz) {
    int t = blockIdx.x * blockDim.x + threadIdx.x;
    if (t >= nnz) return;
    int r = idx[t];
    int c = idx[nnz + t];
    size_t elem = (size_t)r * KF + c;
#if __has_builtin(__builtin_amdgcn_global_atomic_fadd_v2bf16)
    unsigned short wb = f2bf(w[t]);
    s16x2 val;
    if (elem & 1) { val[0] = 0; val[1] = (short)wb; }
    else          { val[0] = (short)wb; val[1] = 0; }
    __builtin_amdgcn_global_atomic_fadd_v2bf16(
        (__attribute__((address_space(1))) s16x2*)(Wb + (elem & ~(size_t)1)), val);
#else
    unsigned* addr = (unsigned*)(Wb + (elem & ~(size_t)1));
    float wf = w[t];
    unsigned old = __hip_atomic_load(addr, __ATOMIC_RELAXED, __HIP_MEMORY_SCOPE_AGENT), assumed;
    do {
        assumed = old;
        unsigned short cur = (elem & 1) ? (unsigned short)(assumed >> 16)
                                        : (unsigned short)(assumed & 0xffffu);
        unsigned short nw = f2bf(bf2f(cur) + wf);
        unsigned newv = (elem & 1) ? ((assumed & 0x0000ffffu) | ((unsigned)nw << 16))
                                   : ((assumed & 0xffff0000u) | (unsigned)nw);
        old = atomicCAS(addr, assumed, newv);
    } while (old != assumed);
#endif
}

// ---------- GEMM: C[M,N] = A[M,K](bf16) * B[N,K]^T(bf16) + bias, fp32 out ----------
// 256x256 tile, 512 threads = 8 waves (2M x 4N), each wave 128x64 output.
// Half-tile (32-k) pipeline, 4 LDS slots x 32 KB, 3 halves staged ahead.
// REGISTER-double-buffered fragments: ds_reads for half g+1 issue BEFORE the MFMA
// clusters of half g, so the LDS pipe (~770 cyc/half) streams under the MFMA pipe
// (~1242 cyc/half). ONE barrier + one counted vmcnt(4) per half. setprio on MFMA.
//
// LDS slot s at byte s*32768: A-half @0 (256 rows x 32k: row*64B), B-half @16384.
// Swizzle: 16B chunk c of row r stored at pos = c ^ ((r>>1)&3) (2-way alias = free).
// Staging is LDS-linear (tid*16B); swizzle applied to the GLOBAL source chunk.
__global__ __launch_bounds__(512, 2) void gemm_bt_bias(
    const unsigned short* __restrict__ A,   // [M_TOK][KF] bf16
    const unsigned short* __restrict__ B,   // [NF][KF] bf16
    const float* __restrict__ bias,
    float* __restrict__ C)
{
    __shared__ unsigned short lds_u[65536];   // 131072 B = 4 slots x 32 KB
    char* const ldsb = (char*)lds_u;

    const int tid  = threadIdx.x;
    const int lane = tid & 63;
    const int wave = tid >> 6;
    const int wm   = wave >> 2;   // 0..1
    const int wn   = wave & 3;    // 0..3

    // 2D XCD partition (bijective): XCD x owns bm in [(x&3)*8,+8), bn in [(x>>2)*8,+8).
    // 32 concurrent blocks/XCD -> per-K-step slab working set 384 KB, L2-resident.
    const int flat = blockIdx.y * 32 + blockIdx.x;
    const int xcd  = flat & 7;
    const int q    = flat >> 3;    // 0..63 within XCD
    const int bm   = (xcd & 3) * 8 + (q & 7);    // 0..31
    const int bn   = (xcd >> 2) * 8 + (q >> 3);  // 0..15

    f32x4 acc[8][4] = {};

    // ---- staging source addressing ----
    // per 8KB region instr: 512 threads x 16B = 128 rows x 64B; row = wave*16 + lane>>2
    const int gc   = (lane & 3) ^ ((lane >> 3) & 3);   // inverse-swizzled source chunk
    const int srow = wave * 16 + (lane >> 2);
    const unsigned short* gA   = A + (size_t)(bm * 256 + srow) * KF + gc * 8;
    const unsigned short* gB   = B + (size_t)(bn * 256 + srow) * KF + gc * 8;
    const unsigned short* gAHi = gA + (size_t)128 * KF;
    const unsigned short* gBHi = gB + (size_t)128 * KF;

    unsigned short* const sd = lds_u + wave * 512;   // wave-uniform dest (+1024B/wave)

    // ---- LDS fragment-read addressing ----
    // A-frag 16x16x32: lane holds [m = lane&15][k = (lane>>4)*8 + j]
    const int fr    = lane & 15;
    const int quad  = lane >> 4;
    const int pos16 = (quad ^ ((fr >> 1) & 3)) << 4;       // swizzled 16B pos (bytes)
    const int rdA   = (wm * 128 + fr) * 64 + pos16;        // + slot_byte + i*1024
    const int rdB   = 16384 + (wn * 64 + fr) * 64 + pos16; // + slot_byte + j*1024

#define STAGE_A(sb, ko) do { \
    load_lds16(gA   + (ko), sd + (((sb)        ) >> 1)); \
    load_lds16(gAHi + (ko), sd + (((sb) +  8192) >> 1)); \
} while (0)
#define STAGE_B(sb, ko) do { \
    load_lds16(gB   + (ko), sd + (((sb) + 16384) >> 1)); \
    load_lds16(gBHi + (ko), sd + (((sb) + 24576) >> 1)); \
} while (0)

#define RD_ALO(dst, sb) do { \
    _Pragma("unroll") \
    for (int _i = 0; _i < 4; ++_i) \
        dst[_i] = *(const bf16x8*)(ldsb + (sb) + rdA + _i * 1024); \
} while (0)

#define RD_AHI(dst, sb) do { \
    _Pragma("unroll") \
    for (int _i = 0; _i < 4; ++_i) \
        dst[_i] = *(const bf16x8*)(ldsb + (sb) + rdA + (4 + _i) * 1024); \
} while (0)

#define RD_B(dst, sb) do { \
    _Pragma("unroll") \
    for (int _j = 0; _j < 4; ++_j) \
        dst[_j] = *(const bf16x8*)(ldsb + (sb) + rdB + _j * 1024); \
} while (0)

#define MFMA16(i0, af, bfv) do { \
    _Pragma("unroll") \
    for (int _i = 0; _i < 4; ++_i) \
        _Pragma("unroll") \
        for (int _j = 0; _j < 4; ++_j) \
            acc[(i0) + _i][_j] = __builtin_amdgcn_mfma_f32_16x16x32_bf16(af[_i], bfv[_j], acc[(i0) + _i][_j], 0, 0, 0); \
} while (0)

    bf16x8 a_lo[4], a_hi[4], b1[4], b2[4];

// One half-tile. BC = B-frag buffer holding b(G); BN = buffer for b(G+1).
// Reads for half G+1 (a_lo, b) issue before/between the MFMA clusters of half G;
// their LDS-pipe time hides under the MFMA-pipe time. One vmcnt + one barrier.
// Hazards: h(G+1) landed at vmcnt(4) of iter G-1 + barrier (RAW ok); staging at
// iter G writes slot (G-1)&3, last read iter G-1, one barrier apart (WAR ok).
#define HALF(G, BC, BN) do { \
    const int sb_  = ((G) & 3) << 15; \
    const int sbn_ = (((G) + 1) & 3) << 15; \
    const int sbs_ = (((G) + 3) & 3) << 15; \
    const int ko_  = ((G) + 3) * 32; \
    STAGE_A(sbs_, ko_); \
    STAGE_B(sbs_, ko_); \
    RD_AHI(a_hi, sb_); \
    RD_B(BN, sbn_); \
    __builtin_amdgcn_s_setprio(1); \
    MFMA16(0, a_lo, BC); \
    __builtin_amdgcn_s_setprio(0); \
    RD_ALO(a_lo, sbn_); \
    __builtin_amdgcn_s_setprio(1); \
    MFMA16(4, a_hi, BC); \
    __builtin_amdgcn_s_setprio(0); \
    VMCNT(4); \
    block_bar(); \
} while (0)

    // ---- prologue: stage halves 0,1,2 into slots 0,1,2 (12 loads) ----
    STAGE_A(0, 0);       STAGE_B(0, 0);
    STAGE_A(32768, 32);  STAGE_B(32768, 32);
    STAGE_A(65536, 64);  STAGE_B(65536, 64);
    VMCNT(4);            // halves 0,1 landed; 2 in flight
    block_bar();
    RD_ALO(a_lo, 0);
    RD_B(b1, 0);

    // ---- main loop: halves 0..123 as 62 even/odd pairs, then peel 124 ----
#pragma unroll 1
    for (int gp = 0; gp < 62; ++gp) {
        const int g = gp * 2;
        HALF(g,     b1, b2);
        HALF(g + 1, b2, b1);
    }
    HALF(124, b1, b2);   // stages half 127 (last)

    // ---- epilogue halves 125,126,127: no staging ----
    {
        // g=125 (b in b2); slot 1 = 32768, next slot 2 = 65536
        RD_AHI(a_hi, 32768);
        RD_B(b1, 65536);
        __builtin_amdgcn_s_setprio(1);
        MFMA16(0, a_lo, b2);
        __builtin_amdgcn_s_setprio(0);
        RD_ALO(a_lo, 65536);
        __builtin_amdgcn_s_setprio(1);
        MFMA16(4, a_hi, b2);
        __builtin_amdgcn_s_setprio(0);
        VMCNT(0);        // half 127 landed
        block_bar();
        // g=126 (b in b1); slot 2 = 65536, next slot 3 = 98304
        RD_AHI(a_hi, 65536);
        RD_B(b2, 98304);
        MFMA16(0, a_lo, b1);
        RD_ALO(a_lo, 98304);
        MFMA16(4, a_hi, b1);
        // g=127 (b in b2); slot 3 = 98304
        RD_AHI(a_hi, 98304);
        MFMA16(0, a_lo, b2);
        MFMA16(4, a_hi, b2);
    }

#undef STAGE_A
#undef STAGE_B
#undef RD_ALO
#undef RD_AHI
#undef RD_B
#undef MFMA16
#undef HALF

    // ---- epilogue: C/D layout col = lane&15, row = (lane>>4)*4 + reg ----
    const int crow = bm * 256 + wm * 128;
    const int ccol = bn * 256 + wn * 64;
    const int r_l  = quad * 4;
#pragma unroll
    for (int j = 0; j < 4; ++j) {
        int col = ccol + j * 16 + fr;
        float bv = bias[col];
#pragma unroll
        for (int i = 0; i < 8; ++i) {
#pragma unroll
            for (int r = 0; r < 4; ++r)
                C[(size_t)(crow + i * 16 + r_l + r) * NF + col] = acc[i][j][r] + bv;
        }
    }
}

// ---------- launch ----------
extern "C" void kernel_launch(void* const* d_in, const int* in_sizes, int n_in,
                              void* d_out, int out_size, void* d_ws, size_t ws_size,
                              hipStream_t stream) {
    const float* x    = (const float*)d_in[0];
    const float* w    = (const float*)d_in[1];
    const float* bias = (const float*)d_in[2];
    const int*   idx  = (const int*)d_in[3];
    float* out = (float*)d_out;
    const int nnz = in_sizes[1];

    // Scratch layout in ws:
    //  - ws + 0      : W bf16  (32MB)
    //  - ws + 32MB   : X bf16  (64MB)
    unsigned short* Wb = (unsigned short*)d_ws;
    unsigned short* Xb = (unsigned short*)((char*)d_ws + (size_t)NF * KF * sizeof(unsigned short));

    const int nx4 = M_TOK * KF / 4;           // X in float4 units
    const int nwb = NF * KF * 2 / 16;         // W bf16 in uint4 units

    // 1) fused: zero bf16 W + convert X -> bf16
    prep_zero_convx<<<(nx4 + 255) / 256, 256, 0, stream>>>(
        (const float4*)x, (ushort4*)Xb, (uint4*)Wb, nx4, nwb);
    // 2) scatter COO straight into bf16 W (duplicates sum via packed-bf16 atomics)
    scatter_bf16<<<(nnz + 255) / 256, 256, 0, stream>>>(idx, w, Wb, nnz);
    // 3) GEMM + bias (overwrites all of d_out; static 128 KiB LDS)
    gemm_bt_bias<<<dim3(32, 16), 512, 0, stream>>>(Xb, Wb, bias, out);
}

// Round 6
// 514.746 us; speedup vs baseline: 1.1545x; 1.0253x over previous
//
#include <hip/hip_runtime.h>

// Problem constants (fixed by reference)
#define M_TOK 8192   // tokens
#define NF    4096   // out features
#define KF    4096   // in features
#define NHALF 128    // 128 half-tiles of 32 k each

typedef __attribute__((ext_vector_type(8))) short bf16x8;  // 8 bf16 = 4 VGPRs
typedef __attribute__((ext_vector_type(4))) float f32x4;   // MFMA accumulator
typedef __attribute__((ext_vector_type(2))) short s16x2;   // packed bf16 pair

// ---------- helpers ----------
__device__ __forceinline__ unsigned short f2bf(float f) {
    unsigned u = __builtin_bit_cast(unsigned, f);
    u += 0x7FFFu + ((u >> 16) & 1u);   // round-to-nearest-even
    return (unsigned short)(u >> 16);
}

__device__ __forceinline__ float bf2f(unsigned short b) {
    unsigned u = ((unsigned)b) << 16;
    return __builtin_bit_cast(float, u);
}

__device__ __forceinline__ void load_lds16(const unsigned short* g, unsigned short* l) {
    // async global->LDS DMA: LDS dest = wave-uniform base + lane*16
    __builtin_amdgcn_global_load_lds(
        (const __attribute__((address_space(1))) unsigned int*)g,
        (__attribute__((address_space(3))) unsigned int*)l,
        16, 0, 0);
}

// raw workgroup barrier that is also a COMPILER memory fence
__device__ __forceinline__ void block_bar() {
    asm volatile("" ::: "memory");
    __builtin_amdgcn_s_barrier();
    asm volatile("" ::: "memory");
}

#define VMCNT(n) asm volatile("s_waitcnt vmcnt(" #n ")" ::: "memory")
// counted LDS wait + scheduler fence (rule #18: MFMA can hoist past asm waitcnt)
#define LGKM(n) do { \
    asm volatile("s_waitcnt lgkmcnt(" #n ")" ::: "memory"); \
    __builtin_amdgcn_sched_barrier(0); \
} while (0)

// ---------- preprocessing ----------
// Fused: zero bf16 dense-W scratch + convert X fp32->bf16. One HBM-bound pass.
__global__ void prep_zero_convx(const float4* __restrict__ X, ushort4* __restrict__ Xb,
                                uint4* __restrict__ Wb, int nx4, int nwb) {
    int i = blockIdx.x * blockDim.x + threadIdx.x;
    if (i < nwb) Wb[i] = (uint4){0u, 0u, 0u, 0u};
    if (i < nx4) {
        float4 v = X[i];
        ushort4 o;
        o.x = f2bf(v.x); o.y = f2bf(v.y); o.z = f2bf(v.z); o.w = f2bf(v.w);
        Xb[i] = o;
    }
}

// Scatter COO directly into bf16 dense W. Duplicates sum atomically.
__global__ void scatter_bf16(const int* __restrict__ idx, const float* __restrict__ w,
                             unsigned short* __restrict__ Wb, int nnz) {
    int t = blockIdx.x * blockDim.x + threadIdx.x;
    if (t >= nnz) return;
    int r = idx[t];
    int c = idx[nnz + t];
    size_t elem = (size_t)r * KF + c;
#if __has_builtin(__builtin_amdgcn_global_atomic_fadd_v2bf16)
    unsigned short wb = f2bf(w[t]);
    s16x2 val;
    if (elem & 1) { val[0] = 0; val[1] = (short)wb; }
    else          { val[0] = (short)wb; val[1] = 0; }
    __builtin_amdgcn_global_atomic_fadd_v2bf16(
        (__attribute__((address_space(1))) s16x2*)(Wb + (elem & ~(size_t)1)), val);
#else
    unsigned* addr = (unsigned*)(Wb + (elem & ~(size_t)1));
    float wf = w[t];
    unsigned old = __hip_atomic_load(addr, __ATOMIC_RELAXED, __HIP_MEMORY_SCOPE_AGENT), assumed;
    do {
        assumed = old;
        unsigned short cur = (elem & 1) ? (unsigned short)(assumed >> 16)
                                        : (unsigned short)(assumed & 0xffffu);
        unsigned short nw = f2bf(bf2f(cur) + wf);
        unsigned newv = (elem & 1) ? ((assumed & 0x0000ffffu) | ((unsigned)nw << 16))
                                   : ((assumed & 0xffff0000u) | (unsigned)nw);
        old = atomicCAS(addr, assumed, newv);
    } while (old != assumed);
#endif
}

// ---------- GEMM: C[M,N] = A[M,K](bf16) * B[N,K]^T(bf16) + bias, fp32 out ----------
// 256x256 tile, 512 threads = 8 waves (2M x 4N), each wave 128x64 output.
// Half-tile (32-k) pipeline, 4 LDS slots x 32 KB, 3 halves staged ahead.
// INLINE-ASM ds_read_b128 + hand-counted lgkmcnt(8) (never 0 in main loop): the 12
// reads/half stream on the LDS pipe UNDER the 32 MFMA/half on the matrix pipe.
// One vmcnt(4) + one s_barrier per half. setprio around MFMA clusters.
//
// LDS slot s at byte s*32768: A-half @0 (256 rows x 32k: row*64B), B-half @16384.
// Swizzle: 16B chunk c of row r stored at pos = c ^ ((r>>1)&3) (2-way alias = free).
// Staging is LDS-linear (tid*16B); swizzle applied to the GLOBAL source chunk.
__global__ __launch_bounds__(512, 2) void gemm_bt_bias(
    const unsigned short* __restrict__ A,   // [M_TOK][KF] bf16
    const unsigned short* __restrict__ B,   // [NF][KF] bf16
    const float* __restrict__ bias,
    float* __restrict__ C)
{
    __shared__ unsigned short lds_u[65536];   // 131072 B = 4 slots x 32 KB

    const int tid  = threadIdx.x;
    const int lane = tid & 63;
    const int wave = tid >> 6;
    const int wm   = wave >> 2;   // 0..1
    const int wn   = wave & 3;    // 0..3

    // 2D XCD partition (bijective): XCD x owns bm in [(x&3)*8,+8), bn in [(x>>2)*8,+8).
    const int flat = blockIdx.y * 32 + blockIdx.x;
    const int xcd  = flat & 7;
    const int q    = flat >> 3;    // 0..63 within XCD
    const int bm   = (xcd & 3) * 8 + (q & 7);    // 0..31
    const int bn   = (xcd >> 2) * 8 + (q >> 3);  // 0..15

    f32x4 acc[8][4] = {};

    // ---- staging source addressing ----
    const int gc   = (lane & 3) ^ ((lane >> 3) & 3);   // inverse-swizzled source chunk
    const int srow = wave * 16 + (lane >> 2);
    const unsigned short* gA   = A + (size_t)(bm * 256 + srow) * KF + gc * 8;
    const unsigned short* gB   = B + (size_t)(bn * 256 + srow) * KF + gc * 8;
    const unsigned short* gAHi = gA + (size_t)128 * KF;
    const unsigned short* gBHi = gB + (size_t)128 * KF;

    unsigned short* const sd = lds_u + wave * 512;   // wave-uniform dest (+1024B/wave)

    // ---- LDS fragment-read addressing (asm, byte addresses in VGPRs) ----
    const int fr    = lane & 15;
    const int quad  = lane >> 4;
    const int pos16 = (quad ^ ((fr >> 1) & 3)) << 4;       // swizzled 16B pos (bytes)
    const int rdA   = (wm * 128 + fr) * 64 + pos16;        // + slot*32768 + i*1024
    const int rdB   = 16384 + (wn * 64 + fr) * 64 + pos16; // + slot*32768 + j*1024

    const unsigned base3 =
        (unsigned)(size_t)(__attribute__((address_space(3))) unsigned short*)lds_u;
    const unsigned aA0 = base3 + (unsigned)rdA;        // slots 0,1 (offset < 64K)
    const unsigned aA1 = aA0 + 65536u;                 // slots 2,3
    const unsigned aB0 = base3 + (unsigned)rdB;
    const unsigned aB1 = aB0 + 65536u;

// asm ds_read_b128 with compile-time offset; slot S in 0..3 must be a constant expr
#define RDA(dst, S, I) \
    asm volatile("ds_read_b128 %0, %1 offset:%2" \
        : "=v"(dst) : "v"((S) >= 2 ? aA1 : aA0), "i"((((S) & 1) * 32768) + (I) * 1024))
#define RDB(dst, S, J) \
    asm volatile("ds_read_b128 %0, %1 offset:%2" \
        : "=v"(dst) : "v"((S) >= 2 ? aB1 : aB0), "i"((((S) & 1) * 32768) + (J) * 1024))
#define RDA4(dst, S, I0) do { \
    RDA(dst[0], S, (I0) + 0); RDA(dst[1], S, (I0) + 1); \
    RDA(dst[2], S, (I0) + 2); RDA(dst[3], S, (I0) + 3); } while (0)
#define RDB4(dst, S) do { \
    RDB(dst[0], S, 0); RDB(dst[1], S, 1); \
    RDB(dst[2], S, 2); RDB(dst[3], S, 3); } while (0)

#define STAGE_A(SB) do { \
    load_lds16(gA,   sd + (((SB)         ) >> 1)); \
    load_lds16(gAHi, sd + (((SB) +  8192) >> 1)); } while (0)
#define STAGE_B(SB) do { \
    load_lds16(gB,   sd + (((SB) + 16384) >> 1)); \
    load_lds16(gBHi, sd + (((SB) + 24576) >> 1)); } while (0)
#define ADV do { gA += 32; gB += 32; gAHi += 32; gBHi += 32; } while (0)

#define MFMA16(i0, af, bfv) do { \
    _Pragma("unroll") \
    for (int _i = 0; _i < 4; ++_i) \
        _Pragma("unroll") \
        for (int _j = 0; _j < 4; ++_j) \
            acc[(i0) + _i][_j] = __builtin_amdgcn_mfma_f32_16x16x32_bf16(af[_i], bfv[_j], acc[(i0) + _i][_j], 0, 0, 0); \
} while (0)

    bf16x8 a_lo[4], a_hi[4], b1[4], b2[4];

// One half-tile at slot SLOT (compile-time 0..3). BC holds b(G); BN gets b(G+1).
// lgkm queue (order): ...a_lo(G)[4] | a_hi(G)[4] b(G+1)[4] | a_lo(G+1)[4]
//   LGKM(8) #1 retires a_lo(G)+b(G)   -> cluster 1 operands ready, 8 in flight
//   LGKM(8) #2 retires a_hi(G)        -> cluster 2 operands ready, 8 in flight
#define HALF(SLOT, BC, BN) do { \
    STAGE_A((((SLOT) + 3) & 3) * 32768); \
    STAGE_B((((SLOT) + 3) & 3) * 32768); \
    ADV; \
    RDA4(a_hi, (SLOT), 4); \
    RDB4(BN, (((SLOT) + 1) & 3)); \
    __builtin_amdgcn_sched_barrier(0); \
    LGKM(8); \
    __builtin_amdgcn_s_setprio(1); \
    MFMA16(0, a_lo, BC); \
    __builtin_amdgcn_s_setprio(0); \
    RDA4(a_lo, (((SLOT) + 1) & 3), 0); \
    __builtin_amdgcn_sched_barrier(0); \
    LGKM(8); \
    __builtin_amdgcn_s_setprio(1); \
    MFMA16(4, a_hi, BC); \
    __builtin_amdgcn_s_setprio(0); \
    VMCNT(4); \
    block_bar(); \
} while (0)

    // ---- prologue: stage halves 0,1,2 into slots 0,1,2 (12 loads) ----
    STAGE_A(0);     STAGE_B(0);     ADV;
    STAGE_A(32768); STAGE_B(32768); ADV;
    STAGE_A(65536); STAGE_B(65536); ADV;
    VMCNT(4);            // halves 0,1 landed; 2 in flight
    block_bar();
    RDA4(a_lo, 0, 0);
    RDB4(b1, 0);

    // ---- main loop: halves 0..123 (31 x 4, slots 0..3), then half 124 ----
#pragma unroll 1
    for (int t = 0; t < 31; ++t) {
        HALF(0, b1, b2);
        HALF(1, b2, b1);
        HALF(2, b1, b2);
        HALF(3, b2, b1);
    }
    HALF(0, b1, b2);     // half 124, stages half 127 into slot 3

    // ---- epilogue halves 125,126,127 (slots 1,2,3): no staging, counted drains ----
    {
        // h125: BC=b2; read b(126)->b1, a_lo(126)
        RDA4(a_hi, 1, 4);
        RDB4(b1, 2);
        __builtin_amdgcn_sched_barrier(0);
        LGKM(8);                 // a_lo(125), b2 ready
        __builtin_amdgcn_s_setprio(1);
        MFMA16(0, a_lo, b2);
        __builtin_amdgcn_s_setprio(0);
        RDA4(a_lo, 2, 0);
        __builtin_amdgcn_sched_barrier(0);
        LGKM(8);                 // a_hi(125) ready
        __builtin_amdgcn_s_setprio(1);
        MFMA16(4, a_hi, b2);
        __builtin_amdgcn_s_setprio(0);
        VMCNT(0);                // half 127 staged data landed
        block_bar();
        // h126: BC=b1; read b(127)->b2, a_lo(127)
        RDA4(a_hi, 2, 4);
        __builtin_amdgcn_sched_barrier(0);
        LGKM(4);                 // b1(126), a_lo(126) ready (a_hi(126) newer)
        __builtin_amdgcn_s_setprio(1);
        MFMA16(0, a_lo, b1);
        __builtin_amdgcn_s_setprio(0);
        RDB4(b2, 3);
        RDA4(a_lo, 3, 0);
        __builtin_amdgcn_sched_barrier(0);
        LGKM(8);                 // a_hi(126) ready
        __builtin_amdgcn_s_setprio(1);
        MFMA16(4, a_hi, b1);
        __builtin_amdgcn_s_setprio(0);
        // h127: BC=b2
        RDA4(a_hi, 3, 4);
        __builtin_amdgcn_sched_barrier(0);
        LGKM(4);                 // b2(127), a_lo(127) ready
        __builtin_amdgcn_s_setprio(1);
        MFMA16(0, a_lo, b2);
        __builtin_amdgcn_s_setprio(0);
        LGKM(0);                 // a_hi(127) ready
        __builtin_amdgcn_s_setprio(1);
        MFMA16(4, a_hi, b2);
        __builtin_amdgcn_s_setprio(0);
    }

#undef RDA
#undef RDB
#undef RDA4
#undef RDB4
#undef STAGE_A
#undef STAGE_B
#undef ADV
#undef MFMA16
#undef HALF

    // ---- epilogue: C/D layout col = lane&15, row = (lane>>4)*4 + reg ----
    const int crow = bm * 256 + wm * 128;
    const int ccol = bn * 256 + wn * 64;
    const int r_l  = quad * 4;
#pragma unroll
    for (int j = 0; j < 4; ++j) {
        int col = ccol + j * 16 + fr;
        float bv = bias[col];
#pragma unroll
        for (int i = 0; i < 8; ++i) {
#pragma unroll
            for (int r = 0; r < 4; ++r)
                C[(size_t)(crow + i * 16 + r_l + r) * NF + col] = acc[i][j][r] + bv;
        }
    }
}

// ---------- launch ----------
extern "C" void kernel_launch(void* const* d_in, const int* in_sizes, int n_in,
                              void* d_out, int out_size, void* d_ws, size_t ws_size,
                              hipStream_t stream) {
    const float* x    = (const float*)d_in[0];
    const float* w    = (const float*)d_in[1];
    const float* bias = (const float*)d_in[2];
    const int*   idx  = (const int*)d_in[3];
    float* out = (float*)d_out;
    const int nnz = in_sizes[1];

    // Scratch layout in ws:
    //  - ws + 0      : W bf16  (32MB)
    //  - ws + 32MB   : X bf16  (64MB)
    unsigned short* Wb = (unsigned short*)d_ws;
    unsigned short* Xb = (unsigned short*)((char*)d_ws + (size_t)NF * KF * sizeof(unsigned short));

    const int nx4 = M_TOK * KF / 4;           // X in float4 units
    const int nwb = NF * KF * 2 / 16;         // W bf16 in uint4 units

    // 1) fused: zero bf16 W + convert X -> bf16
    prep_zero_convx<<<(nx4 + 255) / 256, 256, 0, stream>>>(
        (const float4*)x, (ushort4*)Xb, (uint4*)Wb, nx4, nwb);
    // 2) scatter COO straight into bf16 W (duplicates sum via packed-bf16 atomics)
    scatter_bf16<<<(nnz + 255) / 256, 256, 0, stream>>>(idx, w, Wb, nnz);
    // 3) GEMM + bias (overwrites all of d_out; static 128 KiB LDS)
    gemm_bt_bias<<<dim3(32, 16), 512, 0, stream>>>(Xb, Wb, bias, out);
}